// Round 1
// 115.204 us; speedup vs baseline: 1.0091x; 1.0091x over previous
//
#include <hip/hip_runtime.h>
#include <hip/hip_bf16.h>

static constexpr int N_ = 4;
static constexpr int C_ = 9;
static constexpr int D_ = 16;
static constexpr int HWp = 1024 * 1024;
static constexpr int CELLS = D_ * D_ * D_;  // 4096
static constexpr int PT = HWp / 4;          // 262144 float4 positions per image
static constexpr int TPB = 512;
static constexpr int BPI = 256;             // blocks per image; each block owns 1024 contiguous f4

typedef float f32x4 __attribute__((ext_vector_type(4)));

__device__ __forceinline__ void unpack3(uint2 w, float& x, float& y, float& z) {
    x = __uint_as_float(w.x << 16);
    y = __uint_as_float(w.x & 0xFFFF0000u);
    z = __uint_as_float(w.y << 16);
}

__device__ __forceinline__ float lerp1(float a, float b, float t) {
    return fmaf(b - a, t, a);
}

// Phase 1: fold conv_w into the grid ONCE per image (exact algebraic fold since
// the conv is linear in grid; bf16 quant err <= ~5e-3 << tolerance). Output:
// per-cell uint2 {bf16 x|y, bf16 z} table in workspace. 16384 cells total — ~3 us.
__global__ __launch_bounds__(256) void fold_kernel(
    const float* __restrict__ grid, const float* __restrict__ cw,
    uint2* __restrict__ folded)
{
    const int idx  = blockIdx.x * 256 + threadIdx.x;   // 0 .. N_*CELLS-1
    const int n    = idx >> 12;
    const int cell = idx & (CELLS - 1);
    const float* g = grid + (size_t)n * C_ * CELLS + cell;

    float a0 = 0.f, a1 = 0.f, a2 = 0.f;
#pragma unroll
    for (int c = 0; c < C_; ++c) {
        float v = g[(size_t)c * CELLS];
        a0 = fmaf(cw[c],      v, a0);
        a1 = fmaf(cw[12 + c], v, a1);
        a2 = fmaf(cw[24 + c], v, a2);
    }
    uint2 v;
    v.x = (unsigned)__bfloat16_as_ushort(__float2bfloat16(a0))
        | ((unsigned)__bfloat16_as_ushort(__float2bfloat16(a1)) << 16);
    v.y = (unsigned)__bfloat16_as_ushort(__float2bfloat16(a2));
    folded[idx] = v;
}

// Phase 2: stage the 32 KB folded table into LDS (4x uint4 loads/thread from L2,
// replacing the old per-block 147 KB re-fold), then trilinear-gather from LDS
// while streaming guide->out with non-temporal loads/stores (zero-reuse streams).
__global__ __launch_bounds__(TPB) void slice_kernel(
    const uint2* __restrict__ folded, const float* __restrict__ guide,
    const float* __restrict__ cw, const float* __restrict__ cbias,
    float* __restrict__ out)
{
    __shared__ uint2 sPre[CELLS];  // 32 KB: bf16 x,y,z per cell

    const int n  = blockIdx.x >> 8;        // image
    const int bi = blockIdx.x & (BPI - 1); // tile within image

    // ---- Stage folded table: 2048 uint4, 4 per thread, coalesced ----
    {
        const uint4* src = (const uint4*)(folded + (size_t)n * CELLS);
        uint4* dst = (uint4*)sPre;
#pragma unroll
        for (int k = 0; k < (CELLS / 2) / TPB; ++k) {
            int i = k * TPB + threadIdx.x;
            dst[i] = src[i];
        }
    }
    __syncthreads();

    const f32x4* gR = (const f32x4*)(guide + (size_t)(n * 3 + 0) * HWp);
    const f32x4* gG = (const f32x4*)(guide + (size_t)(n * 3 + 1) * HWp);
    const f32x4* gB = (const f32x4*)(guide + (size_t)(n * 3 + 2) * HWp);
    f32x4* oR = (f32x4*)(out + (size_t)(n * 3 + 0) * HWp);
    f32x4* oG = (f32x4*)(out + (size_t)(n * 3 + 1) * HWp);
    f32x4* oB = (f32x4*)(out + (size_t)(n * 3 + 2) * HWp);

    const float w0r = cw[9],  w0g = cw[10], w0b = cw[11];
    const float w1r = cw[21], w1g = cw[22], w1b = cw[23];
    const float w2r = cw[33], w2g = cw[34], w2b = cw[35];
    const float bi0 = cbias[0], bi1 = cbias[1], bi2 = cbias[2];

    const int base0 = bi * (PT / BPI);  // 1024 contiguous f4 per block

#pragma unroll
    for (int it = 0; it < (PT / BPI) / TPB; ++it) {
        const int p4 = base0 + it * TPB + threadIdx.x;
        f32x4 r4 = __builtin_nontemporal_load(gR + p4);
        f32x4 g4 = __builtin_nontemporal_load(gG + p4);
        f32x4 b4 = __builtin_nontemporal_load(gB + p4);

        float rr[4] = {r4.x, r4.y, r4.z, r4.w};
        float gg[4] = {g4.x, g4.y, g4.z, g4.w};
        float bb[4] = {b4.x, b4.y, b4.z, b4.w};
        float o0[4], o1[4], o2[4];

#pragma unroll
        for (int j = 0; j < 4; ++j) {
            float cr = fminf(fmaxf(rr[j], 0.f), 1.f) * 15.f;
            float cg = fminf(fmaxf(gg[j], 0.f), 1.f) * 15.f;
            float cb = fminf(fmaxf(bb[j], 0.f), 1.f) * 15.f;
            int ir = min((int)cr, 14);
            int ig = min((int)cg, 14);
            int ib = min((int)cb, 14);
            float fr = cr - (float)ir;
            float fg = cg - (float)ig;
            float fb = cb - (float)ib;
            int base = (ir * 16 + ig) * 16 + ib;

            uint2 q000 = sPre[base];
            uint2 q001 = sPre[base + 1];
            uint2 q010 = sPre[base + 16];
            uint2 q011 = sPre[base + 17];
            uint2 q100 = sPre[base + 256];
            uint2 q101 = sPre[base + 257];
            uint2 q110 = sPre[base + 272];
            uint2 q111 = sPre[base + 273];

            float ax, ay, az, bx, by, bz;
            float v00x, v00y, v00z, v01x, v01y, v01z;
            float v10x, v10y, v10z, v11x, v11y, v11z;

            unpack3(q000, ax, ay, az); unpack3(q001, bx, by, bz);
            v00x = lerp1(ax, bx, fb); v00y = lerp1(ay, by, fb); v00z = lerp1(az, bz, fb);
            unpack3(q010, ax, ay, az); unpack3(q011, bx, by, bz);
            v01x = lerp1(ax, bx, fb); v01y = lerp1(ay, by, fb); v01z = lerp1(az, bz, fb);
            unpack3(q100, ax, ay, az); unpack3(q101, bx, by, bz);
            v10x = lerp1(ax, bx, fb); v10y = lerp1(ay, by, fb); v10z = lerp1(az, bz, fb);
            unpack3(q110, ax, ay, az); unpack3(q111, bx, by, bz);
            v11x = lerp1(ax, bx, fb); v11y = lerp1(ay, by, fb); v11z = lerp1(az, bz, fb);

            float v0x = lerp1(v00x, v01x, fg);
            float v0y = lerp1(v00y, v01y, fg);
            float v0z = lerp1(v00z, v01z, fg);
            float v1x = lerp1(v10x, v11x, fg);
            float v1y = lerp1(v10y, v11y, fg);
            float v1z = lerp1(v10z, v11z, fg);

            float vx = lerp1(v0x, v1x, fr);
            float vy = lerp1(v0y, v1y, fr);
            float vz = lerp1(v0z, v1z, fr);

            o0[j] = vx + fmaf(w0r, rr[j], fmaf(w0g, gg[j], fmaf(w0b, bb[j], bi0)));
            o1[j] = vy + fmaf(w1r, rr[j], fmaf(w1g, gg[j], fmaf(w1b, bb[j], bi1)));
            o2[j] = vz + fmaf(w2r, rr[j], fmaf(w2g, gg[j], fmaf(w2b, bb[j], bi2)));
        }

        f32x4 s0 = {o0[0], o0[1], o0[2], o0[3]};
        f32x4 s1 = {o1[0], o1[1], o1[2], o1[3]};
        f32x4 s2 = {o2[0], o2[1], o2[2], o2[3]};
        __builtin_nontemporal_store(s0, oR + p4);
        __builtin_nontemporal_store(s1, oG + p4);
        __builtin_nontemporal_store(s2, oB + p4);
    }
}

extern "C" void kernel_launch(void* const* d_in, const int* in_sizes, int n_in,
                              void* d_out, int out_size, void* d_ws, size_t ws_size,
                              hipStream_t stream) {
    const float* grid  = (const float*)d_in[0];
    const float* guide = (const float*)d_in[1];
    const float* cw    = (const float*)d_in[2];
    const float* cb    = (const float*)d_in[3];
    float* out = (float*)d_out;
    uint2* folded = (uint2*)d_ws;  // N_*CELLS*8 = 131072 B << ws_size

    fold_kernel<<<(N_ * CELLS) / 256, 256, 0, stream>>>(grid, cw, folded);
    slice_kernel<<<N_ * BPI, TPB, 0, stream>>>(folded, guide, cw, cb, out);
}

// Round 2
// 113.301 us; speedup vs baseline: 1.0260x; 1.0168x over previous
//
#include <hip/hip_runtime.h>
#include <hip/hip_bf16.h>

static constexpr int N_ = 4;
static constexpr int C_ = 9;
static constexpr int D_ = 16;
static constexpr int HWp = 1024 * 1024;
static constexpr int CELLS = D_ * D_ * D_;  // 4096
static constexpr int PT = HWp / 4;          // 262144 float4 positions per image
static constexpr int TPB = 512;
static constexpr int BPI = 128;             // 512 blocks total = exactly 2/CU (64 KB LDS each)

typedef float f32x4 __attribute__((ext_vector_type(4)));

__device__ __forceinline__ float lerp1(float a, float b, float t) {
    return fmaf(b - a, t, a);
}

__device__ __forceinline__ unsigned pack2bf(float a, float b) {
    return (unsigned)__bfloat16_as_ushort(__float2bfloat16(a))
         | ((unsigned)__bfloat16_as_ushort(__float2bfloat16(b)) << 16);
}

// Unpack a 16-B pair entry {x0|y0, z0, x1|y1, z1} (corners b and b+1) and do
// the b-lerp in one step.
__device__ __forceinline__ void unpack_lerp(uint4 q, float t,
                                            float& vx, float& vy, float& vz) {
    float ax = __uint_as_float(q.x << 16);
    float ay = __uint_as_float(q.x & 0xFFFF0000u);
    float az = __uint_as_float(q.y << 16);
    float bx = __uint_as_float(q.z << 16);
    float by = __uint_as_float(q.z & 0xFFFF0000u);
    float bz = __uint_as_float(q.w << 16);
    vx = lerp1(ax, bx, t);
    vy = lerp1(ay, by, t);
    vz = lerp1(az, bz, t);
}

// Phase 1: fold conv_w into the grid once per image (conv is linear in grid =>
// exact fold; bf16 quant err ~5e-3 << tol). Emits a PAIR table: entry[cell] =
// folded xyz of cell AND of its b+1 neighbor, 16 B each => one ds_read_b128
// fetches both corners of the innermost lerp. b=15 entries duplicate (never read).
__global__ __launch_bounds__(256) void fold_kernel(
    const float* __restrict__ grid, const float* __restrict__ cw,
    uint4* __restrict__ folded)
{
    const int idx  = blockIdx.x * 256 + threadIdx.x;   // 0 .. N_*CELLS-1
    const int n    = idx >> 12;
    const int cell = idx & (CELLS - 1);
    const int cellN = ((cell & 15) < 15) ? cell + 1 : cell;
    const float* g = grid + (size_t)n * C_ * CELLS;

    float a0 = 0.f, a1 = 0.f, a2 = 0.f;
    float c0 = 0.f, c1 = 0.f, c2 = 0.f;
#pragma unroll
    for (int c = 0; c < C_; ++c) {
        float v = g[(size_t)c * CELLS + cell];
        float w = g[(size_t)c * CELLS + cellN];
        a0 = fmaf(cw[c],      v, a0);
        a1 = fmaf(cw[12 + c], v, a1);
        a2 = fmaf(cw[24 + c], v, a2);
        c0 = fmaf(cw[c],      w, c0);
        c1 = fmaf(cw[12 + c], w, c1);
        c2 = fmaf(cw[24 + c], w, c2);
    }
    uint4 o;
    o.x = pack2bf(a0, a1);
    o.y = (unsigned)__bfloat16_as_ushort(__float2bfloat16(a2));
    o.z = pack2bf(c0, c1);
    o.w = (unsigned)__bfloat16_as_ushort(__float2bfloat16(c2));
    folded[idx] = o;
}

// Phase 2: stage the 64 KB pair table into LDS (coalesced uint4), then
// trilinear-gather with 4x ds_read_b128 per pixel (was 8x ds_read_b64) while
// streaming guide->out with non-temporal loads/stores.
__global__ __launch_bounds__(TPB) void slice_kernel(
    const uint4* __restrict__ folded, const float* __restrict__ guide,
    const float* __restrict__ cw, const float* __restrict__ cbias,
    float* __restrict__ out)
{
    __shared__ uint4 sPre[CELLS];  // 64 KB pair table => 2 blocks/CU

    const int n  = blockIdx.x >> 7;        // image
    const int bi = blockIdx.x & (BPI - 1); // tile within image

    // ---- Stage pair table: 4096 uint4, 8 per thread, coalesced ----
    {
        const uint4* src = folded + (size_t)n * CELLS;
#pragma unroll
        for (int k = 0; k < CELLS / TPB; ++k) {
            int i = k * TPB + threadIdx.x;
            sPre[i] = src[i];
        }
    }
    __syncthreads();

    const f32x4* gR = (const f32x4*)(guide + (size_t)(n * 3 + 0) * HWp);
    const f32x4* gG = (const f32x4*)(guide + (size_t)(n * 3 + 1) * HWp);
    const f32x4* gB = (const f32x4*)(guide + (size_t)(n * 3 + 2) * HWp);
    f32x4* oR = (f32x4*)(out + (size_t)(n * 3 + 0) * HWp);
    f32x4* oG = (f32x4*)(out + (size_t)(n * 3 + 1) * HWp);
    f32x4* oB = (f32x4*)(out + (size_t)(n * 3 + 2) * HWp);

    const float w0r = cw[9],  w0g = cw[10], w0b = cw[11];
    const float w1r = cw[21], w1g = cw[22], w1b = cw[23];
    const float w2r = cw[33], w2g = cw[34], w2b = cw[35];
    const float bi0 = cbias[0], bi1 = cbias[1], bi2 = cbias[2];

    const int base0 = bi * (PT / BPI);  // 2048 contiguous f4 per block

#pragma unroll
    for (int it = 0; it < (PT / BPI) / TPB; ++it) {  // 4 iterations
        const int p4 = base0 + it * TPB + threadIdx.x;
        f32x4 r4 = __builtin_nontemporal_load(gR + p4);
        f32x4 g4 = __builtin_nontemporal_load(gG + p4);
        f32x4 b4 = __builtin_nontemporal_load(gB + p4);

        float rr[4] = {r4.x, r4.y, r4.z, r4.w};
        float gg[4] = {g4.x, g4.y, g4.z, g4.w};
        float bb[4] = {b4.x, b4.y, b4.z, b4.w};
        float o0[4], o1[4], o2[4];

#pragma unroll
        for (int j = 0; j < 4; ++j) {
            float cr = fminf(fmaxf(rr[j], 0.f), 1.f) * 15.f;
            float cg = fminf(fmaxf(gg[j], 0.f), 1.f) * 15.f;
            float cb = fminf(fmaxf(bb[j], 0.f), 1.f) * 15.f;
            int ir = min((int)cr, 14);
            int ig = min((int)cg, 14);
            int ib = min((int)cb, 14);
            float fr = cr - (float)ir;
            float fg = cg - (float)ig;
            float fb = cb - (float)ib;
            int base = (ir * 16 + ig) * 16 + ib;

            uint4 q00 = sPre[base];          // (g+0): corners b, b+1
            uint4 q01 = sPre[base + 16];     // (g+1)
            uint4 q10 = sPre[base + 256];    // (r+1, g+0)
            uint4 q11 = sPre[base + 272];    // (r+1, g+1)

            float v00x, v00y, v00z, v01x, v01y, v01z;
            float v10x, v10y, v10z, v11x, v11y, v11z;
            unpack_lerp(q00, fb, v00x, v00y, v00z);
            unpack_lerp(q01, fb, v01x, v01y, v01z);
            unpack_lerp(q10, fb, v10x, v10y, v10z);
            unpack_lerp(q11, fb, v11x, v11y, v11z);

            float v0x = lerp1(v00x, v01x, fg);
            float v0y = lerp1(v00y, v01y, fg);
            float v0z = lerp1(v00z, v01z, fg);
            float v1x = lerp1(v10x, v11x, fg);
            float v1y = lerp1(v10y, v11y, fg);
            float v1z = lerp1(v10z, v11z, fg);

            float vx = lerp1(v0x, v1x, fr);
            float vy = lerp1(v0y, v1y, fr);
            float vz = lerp1(v0z, v1z, fr);

            o0[j] = vx + fmaf(w0r, rr[j], fmaf(w0g, gg[j], fmaf(w0b, bb[j], bi0)));
            o1[j] = vy + fmaf(w1r, rr[j], fmaf(w1g, gg[j], fmaf(w1b, bb[j], bi1)));
            o2[j] = vz + fmaf(w2r, rr[j], fmaf(w2g, gg[j], fmaf(w2b, bb[j], bi2)));
        }

        f32x4 s0 = {o0[0], o0[1], o0[2], o0[3]};
        f32x4 s1 = {o1[0], o1[1], o1[2], o1[3]};
        f32x4 s2 = {o2[0], o2[1], o2[2], o2[3]};
        __builtin_nontemporal_store(s0, oR + p4);
        __builtin_nontemporal_store(s1, oG + p4);
        __builtin_nontemporal_store(s2, oB + p4);
    }
}

extern "C" void kernel_launch(void* const* d_in, const int* in_sizes, int n_in,
                              void* d_out, int out_size, void* d_ws, size_t ws_size,
                              hipStream_t stream) {
    const float* grid  = (const float*)d_in[0];
    const float* guide = (const float*)d_in[1];
    const float* cw    = (const float*)d_in[2];
    const float* cb    = (const float*)d_in[3];
    float* out = (float*)d_out;
    uint4* folded = (uint4*)d_ws;  // N_*CELLS*16 = 262144 B << ws_size

    fold_kernel<<<(N_ * CELLS) / 256, 256, 0, stream>>>(grid, cw, folded);
    slice_kernel<<<N_ * BPI, TPB, 0, stream>>>(folded, guide, cw, cb, out);
}